// Round 1
// 133.657 us; speedup vs baseline: 1.0168x; 1.0168x over previous
//
#include <hip/hip_runtime.h>
#include <hip/hip_bf16.h>

#define T_SEQ   2048
#define EMBED   1024
#define HD      64
#define NHEADS  16
#define NBH     32            // B*H
// 0.125 * log2(e): fold softmax scale AND exp->exp2 conversion into Q
#define QSCALE  0.18033688011112042f

typedef __attribute__((ext_vector_type(8))) short short8;
typedef __attribute__((ext_vector_type(4))) float f32x4;
typedef __attribute__((ext_vector_type(2))) unsigned int uint2v;
typedef __attribute__((ext_vector_type(4))) unsigned int uint4v;

#if __has_builtin(__builtin_amdgcn_exp2f)
#define EXP2F __builtin_amdgcn_exp2f   // raw v_exp_f32
#else
#define EXP2F exp2f
#endif

// round-half-up bf16
__device__ __forceinline__ ushort bf16r(float f) {
  union { float f; unsigned u; } v; v.f = f;
  return (ushort)((v.u + 0x8000u) >> 16);
}

// pack two floats to bf16x2 (a in low half)
__device__ __forceinline__ unsigned pk2bf_perm(float a, float b) {
  union { float f; unsigned u; } ua, ub; ua.f = a; ub.f = b;
  return __builtin_amdgcn_perm(ub.u + 0x8000u, ua.u + 0x8000u, 0x07060302u);
}
#if __has_builtin(__builtin_amdgcn_cvt_pk_bf16_f32)
typedef __attribute__((ext_vector_type(2))) __bf16 bf16x2;
__device__ __forceinline__ unsigned pkbf(float a, float b) {
  union { bf16x2 v; unsigned u; } c;
  c.v = __builtin_amdgcn_cvt_pk_bf16_f32(a, b);
  return c.u;
}
#else
#define pkbf pk2bf_perm
#endif

// permlane swaps: return {new_vdst, new_vsrc}
// pl32: new_vdst = [d_q0,d_q1,s_q0,s_q1], new_vsrc = [d_q2,d_q3,s_q2,s_q3]
// pl16: new_vdst = [d_g0,s_g0,d_g2,s_g2], new_vsrc = [d_g1,s_g1,d_g3,s_g3]
__device__ __forceinline__ uint2v pl32swap(unsigned a, unsigned b) {
#if __has_builtin(__builtin_amdgcn_permlane32_swap)
  return __builtin_amdgcn_permlane32_swap(a, b, false, false);
#else
  asm("v_permlane32_swap_b32 %0, %1" : "+v"(a), "+v"(b));
  return (uint2v){a, b};
#endif
}
__device__ __forceinline__ uint2v pl16swap(unsigned a, unsigned b) {
#if __has_builtin(__builtin_amdgcn_permlane16_swap)
  return __builtin_amdgcn_permlane16_swap(a, b, false, false);
#else
  asm("v_permlane16_swap_b32 %0, %1" : "+v"(a), "+v"(b));
  return (uint2v){a, b};
#endif
}

// async 16B global->LDS DMA; HW dest = wave-uniform base + lane*16
__device__ __forceinline__ void async16(const ushort* g, ushort* l) {
  __builtin_amdgcn_global_load_lds(
      (const __attribute__((address_space(1))) unsigned int*)g,
      (__attribute__((address_space(3))) unsigned int*)l, 16, 0, 0);
}

// ---------------------------------------------------------------------------
// Kernel 0: W prep: W[d][c] fp32 -> Wg bf16 transposed [c][d], XOR-chunk
// swizzled (phys 8-short chunk = (d>>3) ^ (c&7)).  (unchanged)
// ---------------------------------------------------------------------------
__global__ __launch_bounds__(256) void prep_w(const float* __restrict__ W,
                                              ushort* __restrict__ Wg) {
  const int i = blockIdx.x * 256 + threadIdx.x;    // 48 x 256 = 12288
  const int d = i / 192, c = i - d * 192;
  const int phys = c * 64 + (((d >> 3) ^ (c & 7)) << 3) + (d & 7);
  Wg[phys] = bf16r(W[i]);
}

// ---------------------------------------------------------------------------
// Kernel 1: QKV projection via MFMA 16x16x32 bf16 (unchanged).
// ---------------------------------------------------------------------------
__global__ __launch_bounds__(256) void qkv_proj(
    const float* __restrict__ x, const ushort* __restrict__ Wg,
    const float* __restrict__ bias,
    ushort* __restrict__ Qws, ushort* __restrict__ Kws,
    ushort* __restrict__ Vtws) {
  __shared__ ushort WtL[192 * 64];
  __shared__ float bl[192];

  const int bx = blockIdx.x;         // 1024 = 2b x 16h x 32 t-tiles
  const int b  = bx >> 9;
  const int h  = (bx >> 5) & 15;
  const int t0 = (bx & 31) * 64;
  const int tid = threadIdx.x;
  const int wave = tid >> 6, lane = tid & 63;
  const int quad = lane >> 4, n16 = lane & 15;

  const int trow = t0 + wave * 16 + n16;
  const float* xr = x + ((size_t)(b * T_SEQ + trow)) * EMBED + h * HD;
  short8 xa[2];
#pragma unroll
  for (int ks = 0; ks < 2; ks++) {
    f32x4 v0 = *(const f32x4*)(xr + ks * 32 + quad * 8);
    f32x4 v1 = *(const f32x4*)(xr + ks * 32 + quad * 8 + 4);
    short8 f;
    ((unsigned*)&f)[0] = pkbf(v0[0], v0[1]);
    ((unsigned*)&f)[1] = pkbf(v0[2], v0[3]);
    ((unsigned*)&f)[2] = pkbf(v1[0], v1[1]);
    ((unsigned*)&f)[3] = pkbf(v1[2], v1[3]);
    xa[ks] = f;
  }

#pragma unroll
  for (int it = 0; it < 6; it++)
    async16(Wg + it * 2048 + tid * 8, WtL + it * 2048 + wave * 512);
  if (tid < 192) bl[tid] = bias[tid];
  __syncthreads();

  const int bh = b * NHEADS + h;
  const size_t qkbase = (size_t)bh * T_SEQ * HD;
  const int tw = t0 + wave * 16;
  const int sw = n16 & 7;

#pragma unroll
  for (int nt = 0; nt < 12; nt++) {
    const ushort* wrow = WtL + (nt * 16 + n16) * 64;
    const short8 wb0 = *(short8*)(wrow + ((quad ^ sw) << 3));
    const short8 wb1 = *(short8*)(wrow + (((4 | quad) ^ sw) << 3));
    const float bv = bl[nt * 16 + n16];
    f32x4 acc = (f32x4){0.f, 0.f, 0.f, 0.f};
    acc = __builtin_amdgcn_mfma_f32_16x16x32_bf16(xa[0], wb0, acc, 0, 0, 0);
    acc = __builtin_amdgcn_mfma_f32_16x16x32_bf16(xa[1], wb1, acc, 0, 0, 0);
    if (nt < 4) {
      const int d = nt * 16 + n16;
#pragma unroll
      for (int r = 0; r < 4; r++)
        Qws[qkbase + (size_t)(tw + quad * 4 + r) * HD + d] =
            bf16r((acc[r] + bv) * QSCALE);
    } else if (nt < 8) {
      const int d = (nt - 4) * 16 + n16;
#pragma unroll
      for (int r = 0; r < 4; r++)
        Kws[qkbase + (size_t)(tw + quad * 4 + r) * HD + d] =
            bf16r(acc[r] + bv);
    } else {
      const int d = (nt - 8) * 16 + n16;
      const int tcol = tw + quad * 4;
      uint2v pk;
      pk.x = pkbf(acc[0] + bv, acc[1] + bv);
      pk.y = pkbf(acc[2] + bv, acc[3] + bv);
      *(uint2v*)(Vtws + (size_t)(bh * HD + d) * T_SEQ + tcol) = pk;
    }
  }
}

// ---------------------------------------------------------------------------
// Kernel 2: flash attention, bf16 MFMA 16x16x32.
// R7: BQ=128 per block (4 waves x 32 q-rows in 2 halves) -> 512 blocks;
// K/V LDS frags read ONCE per wave, feed both q-halves (per-q LDS traffic
// and DMA/L2 traffic halved). P never touches LDS: in-register transpose of
// S^T-acc -> A-frag via cvt_pk_bf16 + permlane32_swap + permlane16_swap
// (quad-only routing; n16 = q untouched). LDS = exactly 32 KiB.
// ---------------------------------------------------------------------------
__global__ __launch_bounds__(256) void flash_attn(
    const ushort* __restrict__ Qws, const ushort* __restrict__ Kws,
    const ushort* __restrict__ Vtws, float* __restrict__ out) {
  __shared__ ushort Ks[2][64 * 64];    // 16384 B: [buf][key][d], swizzled
  __shared__ ushort Vs[2][64 * 64];    // 16384 B: [buf][d][key], swizzled

  const int bx = blockIdx.x;
  const int bh = bx & 31;              // all q-tiles of bh -> same XCD (bx%8)
  const int q0 = (bx >> 5) * 128;
  const int b = bh >> 4, h = bh & 15;
  const int tid = threadIdx.x;
  const int wave = tid >> 6, lane = tid & 63;
  const int quad = lane >> 4, n16 = lane & 15;

  const ushort* Qb = Qws + (size_t)bh * T_SEQ * HD;
  const ushort* Kb = Kws + (size_t)bh * T_SEQ * HD;
  const ushort* Vb = Vtws + (size_t)bh * HD * T_SEQ;

  // Q fragments (B-operand of S^T = K Q^T): 32 q-rows per wave, 2 halves
  short8 qa[2][2];
#pragma unroll
  for (int hf = 0; hf < 2; hf++)
#pragma unroll
    for (int ks = 0; ks < 2; ks++) {
      const int row = q0 + wave * 32 + hf * 16 + n16;
      qa[hf][ks] = *(const short8*)(Qb + (size_t)row * HD + ks * 32 + quad * 8);
    }

  // DMA staging source (thread i -> LDS byte i*16), source chunk pre-swizzled
  const int sr = tid >> 3, sp = tid & 7;
  const int sl = (sp ^ (sr & 7)) * 8;
  const ushort* srcK0 = Kb + (size_t)sr * HD + sl;
  const ushort* srcK1 = Kb + (size_t)(sr + 32) * HD + sl;
  const ushort* srcV0 = Vb + (size_t)sr * T_SEQ + sl;
  const ushort* srcV1 = Vb + (size_t)(sr + 32) * T_SEQ + sl;

  // A-frag offsets (row n16 within a 16-row slab, chunk (ks*4+quad)^(n16&7))
  int foff[2];
#pragma unroll
  for (int ks = 0; ks < 2; ks++)
    foff[ks] = n16 * 64 + ((((ks << 2) | quad) ^ (n16 & 7)) << 3);

  f32x4 o[2][4];       // [half][nt]: O frag, q = hf*16 + quad*4+r, d=nt*16+n16
  float ls[2] = {0.f, 0.f};
#pragma unroll
  for (int hf = 0; hf < 2; hf++)
#pragma unroll
    for (int nt = 0; nt < 4; nt++) o[hf][nt] = (f32x4){0.f, 0.f, 0.f, 0.f};

  // prefetch tile 0 into buf 0
  async16(srcK0, Ks[0] + wave * 512);
  async16(srcK1, Ks[0] + 2048 + wave * 512);
  async16(srcV0, Vs[0] + wave * 512);
  async16(srcV1, Vs[0] + 2048 + wave * 512);
  __syncthreads();

  for (int kt = 0; kt < 32; kt++) {
    const int bsel = kt & 1;
    if (kt < 31) {
      const size_t kK = (size_t)(kt + 1) * 64 * HD;
      const size_t kV = (size_t)(kt + 1) * 64;
      async16(srcK0 + kK, Ks[bsel ^ 1] + wave * 512);
      async16(srcK1 + kK, Ks[bsel ^ 1] + 2048 + wave * 512);
      async16(srcV0 + kV, Vs[bsel ^ 1] + wave * 512);
      async16(srcV1 + kV, Vs[bsel ^ 1] + 2048 + wave * 512);
    }
    const ushort* Kt = Ks[bsel];
    const ushort* Vt = Vs[bsel];

    // S^T[key][q] = K * Q^T : A = K slabs (LDS, read once), B = qa (regs)
    f32x4 s0[4], s1[4];
#pragma unroll
    for (int nt = 0; nt < 4; nt++) {
      const short8 ka0 = *(short8*)(Kt + (nt << 10) + foff[0]);
      const short8 ka1 = *(short8*)(Kt + (nt << 10) + foff[1]);
      f32x4 a0 = (f32x4){0.f, 0.f, 0.f, 0.f};
      f32x4 a1 = (f32x4){0.f, 0.f, 0.f, 0.f};
      a0 = __builtin_amdgcn_mfma_f32_16x16x32_bf16(ka0, qa[0][0], a0, 0, 0, 0);
      a0 = __builtin_amdgcn_mfma_f32_16x16x32_bf16(ka1, qa[0][1], a0, 0, 0, 0);
      a1 = __builtin_amdgcn_mfma_f32_16x16x32_bf16(ka0, qa[1][0], a1, 0, 0, 0);
      a1 = __builtin_amdgcn_mfma_f32_16x16x32_bf16(ka1, qa[1][1], a1, 0, 0, 0);
      s0[nt] = a0;
      s1[nt] = a1;
    }

    // p = exp2(s); pack pairs to bf16; transpose across quads in-register:
    //   sources: P01[nt]=pk(p[nt][0],p[nt][1]), P23[nt]=pk(p[nt][2],p[nt][3])
    //   per ks: (A',B') = pl32swap(F[2ks],F[2ks+1]); (w_even,w_odd) =
    //   pl16swap(A',B')  ->  pa_ks dwords [w0,w1,w2,w3], w0/w2 from P01,
    //   w1/w3 from P23.  (keys ks*32+quad*8+j of q-row n16)
    short8 pa[2][2];
#pragma unroll
    for (int hf = 0; hf < 2; hf++) {
      unsigned P01[4], P23[4];
      float lacc = 0.f;
#pragma unroll
      for (int nt = 0; nt < 4; nt++) {
        const f32x4 sv = hf ? s1[nt] : s0[nt];
        float p0 = EXP2F(sv[0]), p1 = EXP2F(sv[1]);
        float p2 = EXP2F(sv[2]), p3 = EXP2F(sv[3]);
        lacc += (p0 + p1) + (p2 + p3);
        P01[nt] = pkbf(p0, p1);
        P23[nt] = pkbf(p2, p3);
      }
      ls[hf] += lacc;
#pragma unroll
      for (int ks = 0; ks < 2; ks++) {
        uint2v tA = pl32swap(P01[2 * ks], P01[2 * ks + 1]);
        uint2v uA = pl16swap(tA.x, tA.y);
        uint2v tB = pl32swap(P23[2 * ks], P23[2 * ks + 1]);
        uint2v uB = pl16swap(tB.x, tB.y);
        union { uint4v u; short8 s; } c;
        c.u = (uint4v){uA.x, uB.x, uA.y, uB.y};
        pa[hf][ks] = c.s;
      }
    }

    // O += P V : A = pa (regs), B = V^T slabs (LDS, read once, both halves)
#pragma unroll
    for (int nt = 0; nt < 4; nt++) {
      const short8 vb0 = *(short8*)(Vt + (nt << 10) + foff[0]);
      const short8 vb1 = *(short8*)(Vt + (nt << 10) + foff[1]);
      o[0][nt] = __builtin_amdgcn_mfma_f32_16x16x32_bf16(pa[0][0], vb0, o[0][nt], 0, 0, 0);
      o[0][nt] = __builtin_amdgcn_mfma_f32_16x16x32_bf16(pa[0][1], vb1, o[0][nt], 0, 0, 0);
      o[1][nt] = __builtin_amdgcn_mfma_f32_16x16x32_bf16(pa[1][0], vb0, o[1][nt], 0, 0, 0);
      o[1][nt] = __builtin_amdgcn_mfma_f32_16x16x32_bf16(pa[1][1], vb1, o[1][nt], 0, 0, 0);
    }
    __syncthreads();   // drains next tile's DMA + protects buffer reuse
  }

  // l: per-lane partial covers quad's keys -> butterfly over quads
#pragma unroll
  for (int hf = 0; hf < 2; hf++) {
    ls[hf] += __shfl_xor(ls[hf], 16, 64);
    ls[hf] += __shfl_xor(ls[hf], 32, 64);
  }

#pragma unroll
  for (int hf = 0; hf < 2; hf++) {
#pragma unroll
    for (int r = 0; r < 4; r++) {
      const float rl = 1.0f / __shfl(ls[hf], quad * 4 + r, 64);
      const int row = q0 + wave * 32 + hf * 16 + quad * 4 + r;
#pragma unroll
      for (int nt = 0; nt < 4; nt++) {
        const int d = nt * 16 + n16;
        out[(size_t)(b * T_SEQ + row) * EMBED + h * HD + d] = o[hf][nt][r] * rl;
      }
    }
  }
}

extern "C" void kernel_launch(void* const* d_in, const int* in_sizes, int n_in,
                              void* d_out, int out_size, void* d_ws, size_t ws_size,
                              hipStream_t stream) {
  (void)in_sizes; (void)n_in; (void)out_size; (void)ws_size;
  const float* x    = (const float*)d_in[0];
  const float* W    = (const float*)d_in[1];
  const float* bias = (const float*)d_in[2];
  float* out = (float*)d_out;

  const size_t elems = (size_t)NBH * T_SEQ * HD;
  ushort* Qws  = (ushort*)d_ws;
  ushort* Kws  = Qws + elems;
  ushort* Vtws = Kws + elems;
  ushort* Wg   = Vtws + elems;       // 24576 shorts

  prep_w<<<dim3(48), dim3(256), 0, stream>>>(W, Wg);
  qkv_proj<<<dim3(1024), dim3(256), 0, stream>>>(x, Wg, bias, Qws, Kws, Vtws);
  flash_attn<<<dim3(512), dim3(256), 0, stream>>>(Qws, Kws, Vtws, out);
}

// Round 2
// 123.696 us; speedup vs baseline: 1.0987x; 1.0805x over previous
//
#include <hip/hip_runtime.h>
#include <hip/hip_bf16.h>

#define T_SEQ   2048
#define EMBED   1024
#define HD      64
#define NHEADS  16
#define NBH     32            // B*H
// 0.125 * log2(e): fold softmax scale AND exp->exp2 conversion into Q
#define QSCALE  0.18033688011112042f

typedef __attribute__((ext_vector_type(8))) short short8;
typedef __attribute__((ext_vector_type(4))) float f32x4;
typedef __attribute__((ext_vector_type(2))) unsigned int uint2v;
typedef __attribute__((ext_vector_type(4))) unsigned int uint4v;

#if __has_builtin(__builtin_amdgcn_exp2f)
#define EXP2F __builtin_amdgcn_exp2f   // raw v_exp_f32
#else
#define EXP2F exp2f
#endif

// round-half-up bf16
__device__ __forceinline__ ushort bf16r(float f) {
  union { float f; unsigned u; } v; v.f = f;
  return (ushort)((v.u + 0x8000u) >> 16);
}

// pack two floats to bf16x2 (a in low half)
__device__ __forceinline__ unsigned pk2bf_perm(float a, float b) {
  union { float f; unsigned u; } ua, ub; ua.f = a; ub.f = b;
  return __builtin_amdgcn_perm(ub.u + 0x8000u, ua.u + 0x8000u, 0x07060302u);
}
#if __has_builtin(__builtin_amdgcn_cvt_pk_bf16_f32)
typedef __attribute__((ext_vector_type(2))) __bf16 bf16x2;
__device__ __forceinline__ unsigned pkbf(float a, float b) {
  union { bf16x2 v; unsigned u; } c;
  c.v = __builtin_amdgcn_cvt_pk_bf16_f32(a, b);
  return c.u;
}
#else
#define pkbf pk2bf_perm
#endif

// permlane swaps: return {new_vdst, new_vsrc}
__device__ __forceinline__ uint2v pl32swap(unsigned a, unsigned b) {
#if __has_builtin(__builtin_amdgcn_permlane32_swap)
  return __builtin_amdgcn_permlane32_swap(a, b, false, false);
#else
  asm("v_permlane32_swap_b32 %0, %1" : "+v"(a), "+v"(b));
  return (uint2v){a, b};
#endif
}
__device__ __forceinline__ uint2v pl16swap(unsigned a, unsigned b) {
#if __has_builtin(__builtin_amdgcn_permlane16_swap)
  return __builtin_amdgcn_permlane16_swap(a, b, false, false);
#else
  asm("v_permlane16_swap_b32 %0, %1" : "+v"(a), "+v"(b));
  return (uint2v){a, b};
#endif
}

// async 16B global->LDS DMA; HW dest = wave-uniform base + lane*16
__device__ __forceinline__ void async16(const ushort* g, ushort* l) {
  __builtin_amdgcn_global_load_lds(
      (const __attribute__((address_space(1))) unsigned int*)g,
      (__attribute__((address_space(3))) unsigned int*)l, 16, 0, 0);
}

// ---------------------------------------------------------------------------
// Kernel 0: W prep: W[d][c] fp32 -> Wg bf16 transposed [c][d], XOR-chunk
// swizzled (phys 8-short chunk = (d>>3) ^ (c&7)).  (unchanged)
// ---------------------------------------------------------------------------
__global__ __launch_bounds__(256) void prep_w(const float* __restrict__ W,
                                              ushort* __restrict__ Wg) {
  const int i = blockIdx.x * 256 + threadIdx.x;    // 48 x 256 = 12288
  const int d = i / 192, c = i - d * 192;
  const int phys = c * 64 + (((d >> 3) ^ (c & 7)) << 3) + (d & 7);
  Wg[phys] = bf16r(W[i]);
}

// ---------------------------------------------------------------------------
// Kernel 1: QKV projection via MFMA 16x16x32 bf16 (unchanged).
// ---------------------------------------------------------------------------
__global__ __launch_bounds__(256) void qkv_proj(
    const float* __restrict__ x, const ushort* __restrict__ Wg,
    const float* __restrict__ bias,
    ushort* __restrict__ Qws, ushort* __restrict__ Kws,
    ushort* __restrict__ Vtws) {
  __shared__ ushort WtL[192 * 64];
  __shared__ float bl[192];

  const int bx = blockIdx.x;         // 1024 = 2b x 16h x 32 t-tiles
  const int b  = bx >> 9;
  const int h  = (bx >> 5) & 15;
  const int t0 = (bx & 31) * 64;
  const int tid = threadIdx.x;
  const int wave = tid >> 6, lane = tid & 63;
  const int quad = lane >> 4, n16 = lane & 15;

  const int trow = t0 + wave * 16 + n16;
  const float* xr = x + ((size_t)(b * T_SEQ + trow)) * EMBED + h * HD;
  short8 xa[2];
#pragma unroll
  for (int ks = 0; ks < 2; ks++) {
    f32x4 v0 = *(const f32x4*)(xr + ks * 32 + quad * 8);
    f32x4 v1 = *(const f32x4*)(xr + ks * 32 + quad * 8 + 4);
    short8 f;
    ((unsigned*)&f)[0] = pkbf(v0[0], v0[1]);
    ((unsigned*)&f)[1] = pkbf(v0[2], v0[3]);
    ((unsigned*)&f)[2] = pkbf(v1[0], v1[1]);
    ((unsigned*)&f)[3] = pkbf(v1[2], v1[3]);
    xa[ks] = f;
  }

#pragma unroll
  for (int it = 0; it < 6; it++)
    async16(Wg + it * 2048 + tid * 8, WtL + it * 2048 + wave * 512);
  if (tid < 192) bl[tid] = bias[tid];
  __syncthreads();

  const int bh = b * NHEADS + h;
  const size_t qkbase = (size_t)bh * T_SEQ * HD;
  const int tw = t0 + wave * 16;
  const int sw = n16 & 7;

#pragma unroll
  for (int nt = 0; nt < 12; nt++) {
    const ushort* wrow = WtL + (nt * 16 + n16) * 64;
    const short8 wb0 = *(short8*)(wrow + ((quad ^ sw) << 3));
    const short8 wb1 = *(short8*)(wrow + (((4 | quad) ^ sw) << 3));
    const float bv = bl[nt * 16 + n16];
    f32x4 acc = (f32x4){0.f, 0.f, 0.f, 0.f};
    acc = __builtin_amdgcn_mfma_f32_16x16x32_bf16(xa[0], wb0, acc, 0, 0, 0);
    acc = __builtin_amdgcn_mfma_f32_16x16x32_bf16(xa[1], wb1, acc, 0, 0, 0);
    if (nt < 4) {
      const int d = nt * 16 + n16;
#pragma unroll
      for (int r = 0; r < 4; r++)
        Qws[qkbase + (size_t)(tw + quad * 4 + r) * HD + d] =
            bf16r((acc[r] + bv) * QSCALE);
    } else if (nt < 8) {
      const int d = (nt - 4) * 16 + n16;
#pragma unroll
      for (int r = 0; r < 4; r++)
        Kws[qkbase + (size_t)(tw + quad * 4 + r) * HD + d] =
            bf16r(acc[r] + bv);
    } else {
      const int d = (nt - 8) * 16 + n16;
      const int tcol = tw + quad * 4;
      uint2v pk;
      pk.x = pkbf(acc[0] + bv, acc[1] + bv);
      pk.y = pkbf(acc[2] + bv, acc[3] + bv);
      *(uint2v*)(Vtws + (size_t)(bh * HD + d) * T_SEQ + tcol) = pk;
    }
  }
}

// ---------------------------------------------------------------------------
// Kernel 2: flash attention, bf16 MFMA 16x16x32.
// R8: counted-vmcnt pipeline (T3+T4): 4 LDS buffers (64 KiB), prefetch
// distance 2, ONE raw s_barrier per iter with s_waitcnt vmcnt(8) (never 0
// until the tail 8->4->0).  Safety: NB=4,D=2 -> all buffer-reuse
// congruences are 3 (mod 4) != 0, so a single barrier per iter suffices
// even with one-iteration wave skew.  setprio(1) around MFMA clusters (T5).
// Row-sum l computed by MFMA with ones-B (shifts VALU adds to the 21%-busy
// MFMA pipe; lane's acc rows == its output rows -> zero epilogue shuffles).
// P stays in registers (cvt_pk + permlane32/16_swap transpose, from R7).
// ---------------------------------------------------------------------------
__global__ __launch_bounds__(256) void flash_attn(
    const ushort* __restrict__ Qws, const ushort* __restrict__ Kws,
    const ushort* __restrict__ Vtws, float* __restrict__ out) {
  __shared__ ushort Ks[4][64 * 64];    // 32768 B: [buf][key][d], swizzled
  __shared__ ushort Vs[4][64 * 64];    // 32768 B: [buf][d][key], swizzled

  const int bx = blockIdx.x;
  const int bh = bx & 31;              // all q-tiles of bh -> same XCD (bx%8)
  const int q0 = (bx >> 5) * 128;
  const int b = bh >> 4, h = bh & 15;
  const int tid = threadIdx.x;
  const int wave = tid >> 6, lane = tid & 63;
  const int quad = lane >> 4, n16 = lane & 15;

  const ushort* Qb = Qws + (size_t)bh * T_SEQ * HD;
  const ushort* Kb = Kws + (size_t)bh * T_SEQ * HD;
  const ushort* Vb = Vtws + (size_t)bh * HD * T_SEQ;

  // Q fragments (B-operand of S^T = K Q^T): 32 q-rows per wave, 2 halves
  short8 qa[2][2];
#pragma unroll
  for (int hf = 0; hf < 2; hf++)
#pragma unroll
    for (int ks = 0; ks < 2; ks++) {
      const int row = q0 + wave * 32 + hf * 16 + n16;
      qa[hf][ks] = *(const short8*)(Qb + (size_t)row * HD + ks * 32 + quad * 8);
    }

  // DMA staging source (thread i -> LDS byte i*16), source chunk pre-swizzled
  const int sr = tid >> 3, sp = tid & 7;
  const int sl = (sp ^ (sr & 7)) * 8;
  const ushort* srcK0 = Kb + (size_t)sr * HD + sl;
  const ushort* srcK1 = Kb + (size_t)(sr + 32) * HD + sl;
  const ushort* srcV0 = Vb + (size_t)sr * T_SEQ + sl;
  const ushort* srcV1 = Vb + (size_t)(sr + 32) * T_SEQ + sl;

  // A-frag offsets (row n16 within a 16-row slab, chunk (ks*4+quad)^(n16&7))
  int foff[2];
#pragma unroll
  for (int ks = 0; ks < 2; ks++)
    foff[ks] = n16 * 64 + ((((ks << 2) | quad) ^ (n16 & 7)) << 3);

  // ones B-frag for row-sum-via-MFMA (bf16 1.0 splat)
  short8 ones;
#pragma unroll
  for (int j = 0; j < 8; j++) ones[j] = (short)0x3F80;

  f32x4 o[2][4];       // [half][nt]: O frag, q = hf*16 + quad*4+r, d=nt*16+n16
  f32x4 lA[2];         // [half]: l acc, q-row quad*4+r in lA[hf][r] (any col)
#pragma unroll
  for (int hf = 0; hf < 2; hf++) {
    lA[hf] = (f32x4){0.f, 0.f, 0.f, 0.f};
#pragma unroll
    for (int nt = 0; nt < 4; nt++) o[hf][nt] = (f32x4){0.f, 0.f, 0.f, 0.f};
  }

  // prologue: prefetch tiles 0,1 into bufs 0,1 (no barrier; iter-0 handles it)
  async16(srcK0, Ks[0] + wave * 512);
  async16(srcK1, Ks[0] + 2048 + wave * 512);
  async16(srcV0, Vs[0] + wave * 512);
  async16(srcV1, Vs[0] + 2048 + wave * 512);
  async16(srcK0 + 64 * HD, Ks[1] + wave * 512);
  async16(srcK1 + 64 * HD, Ks[1] + 2048 + wave * 512);
  async16(srcV0 + 64, Vs[1] + wave * 512);
  async16(srcV1 + 64, Vs[1] + 2048 + wave * 512);

  for (int kt = 0; kt < 32; kt++) {
    const int cb = kt & 3;
    if (kt < 30) {
      const int pb = (kt + 2) & 3;
      const size_t kK = (size_t)(kt + 2) * 64 * HD;
      const size_t kV = (size_t)(kt + 2) * 64;
      async16(srcK0 + kK, Ks[pb] + wave * 512);
      async16(srcK1 + kK, Ks[pb] + 2048 + wave * 512);
      async16(srcV0 + kV, Vs[pb] + wave * 512);
      async16(srcV1 + kV, Vs[pb] + 2048 + wave * 512);
    }
    __builtin_amdgcn_sched_barrier(0);
    // counted drain: tile kt's 4 DMAs complete; tiles kt+1,kt+2 stay in flight
    if (kt < 30)       asm volatile("s_waitcnt vmcnt(8)" ::: "memory");
    else if (kt == 30) asm volatile("s_waitcnt vmcnt(4)" ::: "memory");
    else               asm volatile("s_waitcnt vmcnt(0)" ::: "memory");
    __builtin_amdgcn_s_barrier();
    __builtin_amdgcn_sched_barrier(0);

    const ushort* Kt = Ks[cb];
    const ushort* Vt = Vs[cb];

    // S^T[key][q] = K * Q^T : A = K slabs (LDS, read once), B = qa (regs)
    f32x4 s0[4], s1[4];
    __builtin_amdgcn_s_setprio(1);
#pragma unroll
    for (int nt = 0; nt < 4; nt++) {
      const short8 ka0 = *(short8*)(Kt + (nt << 10) + foff[0]);
      const short8 ka1 = *(short8*)(Kt + (nt << 10) + foff[1]);
      f32x4 a0 = (f32x4){0.f, 0.f, 0.f, 0.f};
      f32x4 a1 = (f32x4){0.f, 0.f, 0.f, 0.f};
      a0 = __builtin_amdgcn_mfma_f32_16x16x32_bf16(ka0, qa[0][0], a0, 0, 0, 0);
      a0 = __builtin_amdgcn_mfma_f32_16x16x32_bf16(ka1, qa[0][1], a0, 0, 0, 0);
      a1 = __builtin_amdgcn_mfma_f32_16x16x32_bf16(ka0, qa[1][0], a1, 0, 0, 0);
      a1 = __builtin_amdgcn_mfma_f32_16x16x32_bf16(ka1, qa[1][1], a1, 0, 0, 0);
      s0[nt] = a0;
      s1[nt] = a1;
    }
    __builtin_amdgcn_s_setprio(0);

    // p = exp2(s); pack pairs to bf16; transpose across quads in-register
    short8 pa[2][2];
#pragma unroll
    for (int hf = 0; hf < 2; hf++) {
      unsigned P01[4], P23[4];
#pragma unroll
      for (int nt = 0; nt < 4; nt++) {
        const f32x4 sv = hf ? s1[nt] : s0[nt];
        float p0 = EXP2F(sv[0]), p1 = EXP2F(sv[1]);
        float p2 = EXP2F(sv[2]), p3 = EXP2F(sv[3]);
        P01[nt] = pkbf(p0, p1);
        P23[nt] = pkbf(p2, p3);
      }
#pragma unroll
      for (int ks = 0; ks < 2; ks++) {
        uint2v tA = pl32swap(P01[2 * ks], P01[2 * ks + 1]);
        uint2v uA = pl16swap(tA.x, tA.y);
        uint2v tB = pl32swap(P23[2 * ks], P23[2 * ks + 1]);
        uint2v uB = pl16swap(tB.x, tB.y);
        union { uint4v u; short8 s; } c;
        c.u = (uint4v){uA.x, uB.x, uA.y, uB.y};
        pa[hf][ks] = c.s;
      }
    }

    // O += P V ; l += P 1  (A = pa regs, B = V^T slabs / ones)
    __builtin_amdgcn_s_setprio(1);
#pragma unroll
    for (int nt = 0; nt < 4; nt++) {
      const short8 vb0 = *(short8*)(Vt + (nt << 10) + foff[0]);
      const short8 vb1 = *(short8*)(Vt + (nt << 10) + foff[1]);
      o[0][nt] = __builtin_amdgcn_mfma_f32_16x16x32_bf16(pa[0][0], vb0, o[0][nt], 0, 0, 0);
      o[0][nt] = __builtin_amdgcn_mfma_f32_16x16x32_bf16(pa[0][1], vb1, o[0][nt], 0, 0, 0);
      o[1][nt] = __builtin_amdgcn_mfma_f32_16x16x32_bf16(pa[1][0], vb0, o[1][nt], 0, 0, 0);
      o[1][nt] = __builtin_amdgcn_mfma_f32_16x16x32_bf16(pa[1][1], vb1, o[1][nt], 0, 0, 0);
    }
#pragma unroll
    for (int hf = 0; hf < 2; hf++) {
      lA[hf] = __builtin_amdgcn_mfma_f32_16x16x32_bf16(pa[hf][0], ones, lA[hf], 0, 0, 0);
      lA[hf] = __builtin_amdgcn_mfma_f32_16x16x32_bf16(pa[hf][1], ones, lA[hf], 0, 0, 0);
    }
    __builtin_amdgcn_s_setprio(0);
    // no trailing barrier: NB=4, D=2 makes next iter's DMA target a buffer
    // whose readers finished before the top-of-iter barrier (3 mod 4 != 0)
  }

  // epilogue: lane (quad,n16) holds o rows quad*4+r and l rows quad*4+r
#pragma unroll
  for (int hf = 0; hf < 2; hf++) {
#pragma unroll
    for (int r = 0; r < 4; r++) {
      const float rl = 1.0f / lA[hf][r];
      const int row = q0 + wave * 32 + hf * 16 + quad * 4 + r;
#pragma unroll
      for (int nt = 0; nt < 4; nt++) {
        const int d = nt * 16 + n16;
        out[(size_t)(b * T_SEQ + row) * EMBED + h * HD + d] = o[hf][nt][r] * rl;
      }
    }
  }
}

extern "C" void kernel_launch(void* const* d_in, const int* in_sizes, int n_in,
                              void* d_out, int out_size, void* d_ws, size_t ws_size,
                              hipStream_t stream) {
  (void)in_sizes; (void)n_in; (void)out_size; (void)ws_size;
  const float* x    = (const float*)d_in[0];
  const float* W    = (const float*)d_in[1];
  const float* bias = (const float*)d_in[2];
  float* out = (float*)d_out;

  const size_t elems = (size_t)NBH * T_SEQ * HD;
  ushort* Qws  = (ushort*)d_ws;
  ushort* Kws  = Qws + elems;
  ushort* Vtws = Kws + elems;
  ushort* Wg   = Vtws + elems;       // 24576 shorts

  prep_w<<<dim3(48), dim3(256), 0, stream>>>(W, Wg);
  qkv_proj<<<dim3(1024), dim3(256), 0, stream>>>(x, Wg, bias, Qws, Kws, Vtws);
  flash_attn<<<dim3(512), dim3(256), 0, stream>>>(Qws, Kws, Vtws, out);
}